// Round 1
// baseline (264.130 us; speedup 1.0000x reference)
//
#include <hip/hip_runtime.h>
#include <hip/hip_bf16.h>

// FactorizedGenerator: per-coordinate MLP 8 -> 64 -> 64 -> 64 -> 1 (SiLU), D=256 coords, B=4096.
// Strategy: split-bf16 (hi+lo) MFMA emulation of fp32 GEMMs.
//   - setup kernel: fp32 weights -> per-d packed bf16 hi/lo records (transposed, padded) in d_ws
//   - main kernel: one block = (one d, 128 batch rows); transposed compute D = W^T @ H^T so the
//     MFMA D-layout (4 consecutive features per lane) packs straight into b64 LDS writes.

#define NDIM 256
#define LDIM 8
#define HDIM 64
#define BDIM 4096
#define BT   128

// per-d weight record layout (bytes); all row strides are 16B multiples
#define REC_W1P   0        // [64][40] bf16: out-feat major; kslots 0-7 W1hi, 8-15 W1hi, 16-23 W1lo, 24-39 zero
#define REC_W2H   5120     // [64][72] bf16: W2hi^T (o,i), cols 64-71 zero pad
#define REC_W2L   14336
#define REC_W3H   23552
#define REC_W3L   32768
#define REC_COEF  41984    // 320 f32: [0,64) b1, [64,128) b2, [128,192) b3, [192,256) Wo, [256] bo
#define REC_SIZE  43264    // = 2704 * 16

#define ACT_STR   136      // act row stride in bf16 elems (64 hi + 64 lo + 8 pad); 272B = 17*16B, 2-way banks
#define LDS_ACT   REC_SIZE
#define LDS_OUT   (LDS_ACT + BT * ACT_STR * 2)   // 78080
#define LDS_SIZE  (LDS_OUT + 256 * 4)            // 79104 B -> 2 blocks/CU

typedef __bf16 bf16x8 __attribute__((ext_vector_type(8)));
typedef __bf16 bf16x4 __attribute__((ext_vector_type(4)));
typedef float  f32x4  __attribute__((ext_vector_type(4)));

__device__ __forceinline__ __bf16 bhi(float f) { return (__bf16)f; }
__device__ __forceinline__ __bf16 blo(float f, __bf16 h) { return (__bf16)(f - (float)h); }
__device__ __forceinline__ float silu_f(float x) { return x / (1.0f + __expf(-x)); }

// ---------------------------------------------------------------------------
// setup: fp32 -> packed bf16 hi/lo records, one block per d
// ---------------------------------------------------------------------------
__global__ void setup_weights(const float* __restrict__ W1, const float* __restrict__ b1,
                              const float* __restrict__ W2, const float* __restrict__ b2,
                              const float* __restrict__ W3, const float* __restrict__ b3,
                              const float* __restrict__ Wo, const float* __restrict__ bo,
                              char* __restrict__ ws) {
  const int d = blockIdx.x;
  const int t = threadIdx.x;
  __shared__ float tile[64 * 65];   // padded fp32 transpose tile

  char* rec = ws + (size_t)d * REC_SIZE;
  __bf16* w1p = (__bf16*)(rec + REC_W1P);
  __bf16* w2h = (__bf16*)(rec + REC_W2H);
  __bf16* w2l = (__bf16*)(rec + REC_W2L);
  __bf16* w3h = (__bf16*)(rec + REC_W3H);
  __bf16* w3l = (__bf16*)(rec + REC_W3L);
  float*  coef = (float*)(rec + REC_COEF);

  // ---- W1 (8x64) ----
  for (int idx = t; idx < LDIM * HDIM; idx += 256)
    tile[(idx >> 6) * 65 + (idx & 63)] = W1[d * LDIM * HDIM + idx];
  __syncthreads();
  for (int idx = t; idx < 64 * 40; idx += 256) {
    int o = idx / 40, ks = idx - o * 40;
    __bf16 v = (__bf16)0.0f;
    if (ks < 8)       { v = bhi(tile[ks * 65 + o]); }
    else if (ks < 16) { v = bhi(tile[(ks - 8) * 65 + o]); }
    else if (ks < 24) { float f = tile[(ks - 16) * 65 + o]; v = blo(f, bhi(f)); }
    w1p[o * 40 + ks] = v;
  }
  __syncthreads();

  // ---- W2 (64x64) ----
  for (int idx = t; idx < 4096; idx += 256)
    tile[(idx >> 6) * 65 + (idx & 63)] = W2[d * 4096 + idx];
  __syncthreads();
  for (int idx = t; idx < 64 * 72; idx += 256) {
    int o = idx / 72, i = idx - o * 72;
    __bf16 vh = (__bf16)0.0f, vl = (__bf16)0.0f;
    if (i < 64) { float f = tile[i * 65 + o]; vh = bhi(f); vl = blo(f, vh); }
    w2h[o * 72 + i] = vh;
    w2l[o * 72 + i] = vl;
  }
  __syncthreads();

  // ---- W3 (64x64) ----
  for (int idx = t; idx < 4096; idx += 256)
    tile[(idx >> 6) * 65 + (idx & 63)] = W3[d * 4096 + idx];
  __syncthreads();
  for (int idx = t; idx < 64 * 72; idx += 256) {
    int o = idx / 72, i = idx - o * 72;
    __bf16 vh = (__bf16)0.0f, vl = (__bf16)0.0f;
    if (i < 64) { float f = tile[i * 65 + o]; vh = bhi(f); vl = blo(f, vh); }
    w3h[o * 72 + i] = vh;
    w3l[o * 72 + i] = vl;
  }

  // ---- coef ----
  if (t < 64)       coef[t] = b1[d * 64 + t];
  else if (t < 128) coef[t] = b2[d * 64 + (t - 64)];
  else if (t < 192) coef[t] = b3[d * 64 + (t - 128)];
  else if (t < 256) coef[t] = Wo[d * 64 + (t - 192)];
  if (t == 0) coef[256] = bo[d];
  if (t >= 1 && t < 64) coef[256 + t] = 0.0f;
}

// ---------------------------------------------------------------------------
// main kernel helpers
// ---------------------------------------------------------------------------
// mid layer: acc[mt][nt] = sum_k Wt[m][k]*act[n][k], split terms hh + h*lo + lo*h
__device__ __forceinline__ void mid_layer(const __bf16* __restrict__ wh, const __bf16* __restrict__ wl,
                                          const __bf16* __restrict__ act, f32x4 (&acc)[2][4],
                                          int wm, int wp, int l15, int lg) {
#pragma unroll
  for (int mt = 0; mt < 2; ++mt)
#pragma unroll
    for (int nt = 0; nt < 4; ++nt) acc[mt][nt] = (f32x4){0.0f, 0.0f, 0.0f, 0.0f};

#pragma unroll
  for (int ks = 0; ks < 2; ++ks) {
    bf16x8 ah[2], al[2], bh[4], bl[4];
#pragma unroll
    for (int mt = 0; mt < 2; ++mt) {
      const int m = wm * 32 + mt * 16 + l15;
      ah[mt] = *(const bf16x8*)(wh + m * 72 + ks * 32 + lg * 8);
      al[mt] = *(const bf16x8*)(wl + m * 72 + ks * 32 + lg * 8);
    }
#pragma unroll
    for (int nt = 0; nt < 4; ++nt) {
      const int r = wp * 64 + nt * 16 + l15;
      bh[nt] = *(const bf16x8*)(act + r * ACT_STR + ks * 32 + lg * 8);
      bl[nt] = *(const bf16x8*)(act + r * ACT_STR + 64 + ks * 32 + lg * 8);
    }
#pragma unroll
    for (int mt = 0; mt < 2; ++mt)
#pragma unroll
      for (int nt = 0; nt < 4; ++nt)
        acc[mt][nt] = __builtin_amdgcn_mfma_f32_16x16x32_bf16(ah[mt], bh[nt], acc[mt][nt], 0, 0, 0);
#pragma unroll
    for (int mt = 0; mt < 2; ++mt)
#pragma unroll
      for (int nt = 0; nt < 4; ++nt)
        acc[mt][nt] = __builtin_amdgcn_mfma_f32_16x16x32_bf16(ah[mt], bl[nt], acc[mt][nt], 0, 0, 0);
#pragma unroll
    for (int mt = 0; mt < 2; ++mt)
#pragma unroll
      for (int nt = 0; nt < 4; ++nt)
        acc[mt][nt] = __builtin_amdgcn_mfma_f32_16x16x32_bf16(al[mt], bh[nt], acc[mt][nt], 0, 0, 0);
  }
}

// bias + SiLU + bf16 hi/lo split, packed b64 stores into act[row][feat]
__device__ __forceinline__ void transition(f32x4 (&acc)[2][4], const float* __restrict__ bias,
                                           __bf16* __restrict__ act, int wm, int wp, int l15, int lg) {
#pragma unroll
  for (int mt = 0; mt < 2; ++mt) {
    const int f0 = wm * 32 + mt * 16 + lg * 4;
#pragma unroll
    for (int nt = 0; nt < 4; ++nt) {
      const int r = wp * 64 + nt * 16 + l15;
      bf16x4 hv, lv;
#pragma unroll
      for (int i = 0; i < 4; ++i) {
        float x = acc[mt][nt][i] + bias[f0 + i];
        float s = silu_f(x);
        __bf16 h = bhi(s);
        hv[i] = h;
        lv[i] = blo(s, h);
      }
      *(bf16x4*)(act + r * ACT_STR + f0) = hv;
      *(bf16x4*)(act + r * ACT_STR + 64 + f0) = lv;
    }
  }
}

// ---------------------------------------------------------------------------
// main: one block per (d, 128-row batch tile); 4 waves = 2 row-halves x 2 feat-halves
// ---------------------------------------------------------------------------
__global__ __launch_bounds__(256, 2)
void mlp_main(const float* __restrict__ z, const char* __restrict__ ws, float* __restrict__ out) {
  __shared__ __align__(16) char smem[LDS_SIZE];

  // XCD-chunked bijective swizzle: 8192 blocks, 1024 per XCD -> each XCD owns contiguous d-range
  const int bx  = (int)blockIdx.x;
  const int swz = (bx & 7) * 1024 + (bx >> 3);
  const int d   = swz >> 5;
  const int b0  = (swz & 31) * BT;

  const int t    = (int)threadIdx.x;
  const int lane = t & 63;
  const int wave = t >> 6;
  const int wm  = wave & 1;   // feature half: feats [wm*32, wm*32+32)
  const int wp  = wave >> 1;  // row half: rows [wp*64, wp*64+64)
  const int l15 = lane & 15;
  const int lg  = lane >> 4;

  // ---- stage this d's weight record (linear copy, 43264 B) ----
  {
    const float4* gsrc = (const float4*)(ws + (size_t)d * REC_SIZE);
    float4* ldst = (float4*)smem;
    for (int i = t; i < REC_SIZE / 16; i += 256) ldst[i] = gsrc[i];
  }
  __syncthreads();  // A

  const __bf16* w1p  = (const __bf16*)(smem + REC_W1P);
  const __bf16* w2h  = (const __bf16*)(smem + REC_W2H);
  const __bf16* w2l  = (const __bf16*)(smem + REC_W2L);
  const __bf16* w3h  = (const __bf16*)(smem + REC_W3H);
  const __bf16* w3l  = (const __bf16*)(smem + REC_W3L);
  const float*  coef = (const float*)(smem + REC_COEF);
  __bf16* act    = (__bf16*)(smem + LDS_ACT);
  float*  outBuf = (float*)(smem + LDS_OUT);

  f32x4 acc[2][4];

  // ---- layer 1: K=32 packs [z_hi | z_lo | z_hi | 0] x [W1hi | W1hi | W1lo | 0] ----
  bf16x8 a1[2];
#pragma unroll
  for (int mt = 0; mt < 2; ++mt) {
    const int m = wm * 32 + mt * 16 + l15;
    a1[mt] = *(const bf16x8*)(w1p + m * 40 + lg * 8);
  }
  bf16x8 zf[4];
#pragma unroll
  for (int nt = 0; nt < 4; ++nt) {
    const int r = b0 + wp * 64 + nt * 16 + l15;
    const float* zp = z + ((size_t)r * NDIM + d) * LDIM;
    float4 q0 = *(const float4*)zp;
    float4 q1 = *(const float4*)(zp + 4);
    float zv[8] = {q0.x, q0.y, q0.z, q0.w, q1.x, q1.y, q1.z, q1.w};
    bf16x8 v;
#pragma unroll
    for (int j = 0; j < 8; ++j) {
      float f = zv[j];
      __bf16 h = bhi(f);
      __bf16 l = blo(f, h);
      __bf16 val = (lg == 1) ? l : h;
      v[j] = (lg == 3) ? (__bf16)0.0f : val;
    }
    zf[nt] = v;
  }
#pragma unroll
  for (int mt = 0; mt < 2; ++mt)
#pragma unroll
    for (int nt = 0; nt < 4; ++nt) {
      f32x4 zc = {0.0f, 0.0f, 0.0f, 0.0f};
      acc[mt][nt] = __builtin_amdgcn_mfma_f32_16x16x32_bf16(a1[mt], zf[nt], zc, 0, 0, 0);
    }

  transition(acc, coef + 0, act, wm, wp, l15, lg);
  __syncthreads();  // B: act1 ready

  // ---- layer 2 ----
  mid_layer(w2h, w2l, act, acc, wm, wp, l15, lg);
  __syncthreads();  // C: all reads of act1 done before overwrite
  transition(acc, coef + 64, act, wm, wp, l15, lg);
  __syncthreads();  // D: act2 ready

  // ---- layer 3 ----
  mid_layer(w3h, w3l, act, acc, wm, wp, l15, lg);

  // ---- output layer: out[r] = sum_f silu(h3 + b3[f]) * Wo[f] + bo ----
  const float* b3c = coef + 128;
  const float* woc = coef + 192;
#pragma unroll
  for (int nt = 0; nt < 4; ++nt) {
    float part = 0.0f;
#pragma unroll
    for (int mt = 0; mt < 2; ++mt) {
      const int f0 = wm * 32 + mt * 16 + lg * 4;
#pragma unroll
      for (int i = 0; i < 4; ++i) {
        float x = acc[mt][nt][i] + b3c[f0 + i];
        part += silu_f(x) * woc[f0 + i];
      }
    }
    part += __shfl_xor(part, 16);
    part += __shfl_xor(part, 32);
    if (lg == 0) outBuf[wm * 128 + wp * 64 + nt * 16 + l15] = part;
  }
  __syncthreads();  // E
  if (t < BT) out[(size_t)(b0 + t) * NDIM + d] = outBuf[t] + outBuf[128 + t] + coef[256];
}

// ---------------------------------------------------------------------------
extern "C" void kernel_launch(void* const* d_in, const int* in_sizes, int n_in,
                              void* d_out, int out_size, void* d_ws, size_t ws_size,
                              hipStream_t stream) {
  const float* z  = (const float*)d_in[0];
  const float* W1 = (const float*)d_in[1];
  const float* b1 = (const float*)d_in[2];
  const float* W2 = (const float*)d_in[3];
  const float* b2 = (const float*)d_in[4];
  const float* W3 = (const float*)d_in[5];
  const float* b3 = (const float*)d_in[6];
  const float* Wo = (const float*)d_in[7];
  const float* bo = (const float*)d_in[8];
  float* out = (float*)d_out;

  setup_weights<<<NDIM, 256, 0, stream>>>(W1, b1, W2, b2, W3, b3, Wo, bo, (char*)d_ws);
  mlp_main<<<NDIM * (BDIM / BT), 256, 0, stream>>>(z, (const char*)d_ws, out);
}

// Round 5
// 214.600 us; speedup vs baseline: 1.2308x; 1.2308x over previous
//
#include <hip/hip_runtime.h>
#include <hip/hip_bf16.h>

// FactorizedGenerator: per-coordinate MLP 8 -> 64 -> 64 -> 64 -> 1 (SiLU), D=256, B=4096.
// Split-bf16 (hi+lo) MFMA emulation of fp32 GEMMs, transposed compute D = W^T @ H^T.
// R3 (2nd resubmit; R3/R4 benches were infra failures): fix LDS overflow (outBuf needs
// 1024B), drop zpack (z split folded into mlp_main), keep XOR chunk-swizzled LDS,
// bias-in-accumulator, lean rcp-silu.

#define NDIM 256
#define LDIM 8
#define HDIM 64
#define BDIM 4096
#define BT   128

// per-d weight record layout (bytes)
#define REC_W1P   0        // [64][24] bf16: ks 0-7 W1hi, 8-15 W1hi, 16-23 W1lo  (A lg==3 -> zero frag)
#define REC_W2H   3072     // [64][64] bf16 W^T, 16B-chunk XOR swizzle: pos = chunk ^ (row&7)
#define REC_W2L   11264    // = W2H + 8192
#define REC_W3H   19456
#define REC_W3L   27648
#define REC_COEF  35840    // 256 f32: [0,64) b1, [64,128) b2, [128,192) b3, [192,256) Wo
#define REC_SIZE  36864    // = 2304 * 16

#define ACT_HI    36864    // [128][64] bf16, same XOR swizzle; lo twin at +16384
#define ACT_LO    53248
#define OUTBUF    69632    // 256 f32 (two wm-halves of 128)
#define LDS_SIZE  70656

typedef __bf16 bf16x8 __attribute__((ext_vector_type(8)));
typedef __bf16 bf16x4 __attribute__((ext_vector_type(4)));
typedef float  f32x4  __attribute__((ext_vector_type(4)));

__device__ __forceinline__ float silu_f(float x) {
  return x * __builtin_amdgcn_rcpf(1.0f + __expf(-x));
}

// ---------------------------------------------------------------------------
// setup: fp32 weights -> packed/swizzled bf16 hi/lo records. grid (256, 3).
// ---------------------------------------------------------------------------
__global__ void setup_weights(const float* __restrict__ W1, const float* __restrict__ b1,
                              const float* __restrict__ W2, const float* __restrict__ b2,
                              const float* __restrict__ W3, const float* __restrict__ b3,
                              const float* __restrict__ Wo, char* __restrict__ ws) {
  const int d = blockIdx.x;
  const int y = blockIdx.y;
  const int t = threadIdx.x;
  __shared__ float tile[64 * 65];
  char* rec = ws + (size_t)d * REC_SIZE;

  if (y == 0) {
    // W1 (8x64) + coef
    for (int idx = t; idx < LDIM * HDIM; idx += 256)
      tile[(idx >> 6) * 65 + (idx & 63)] = W1[d * LDIM * HDIM + idx];   // tile[l][o]
    __syncthreads();
    if (t < 64) {
      __bf16* w1p = (__bf16*)(rec + REC_W1P) + t * 24;
#pragma unroll
      for (int ks = 0; ks < 8; ++ks) {
        float f = tile[ks * 65 + t];
        __bf16 h = (__bf16)f;
        w1p[ks] = h;
        w1p[8 + ks] = h;
        w1p[16 + ks] = (__bf16)(f - (float)h);
      }
    }
    float* coef = (float*)(rec + REC_COEF);
    float v;
    if (t < 64)       v = b1[d * 64 + t];
    else if (t < 128) v = b2[d * 64 + (t - 64)];
    else if (t < 192) v = b3[d * 64 + (t - 128)];
    else              v = Wo[d * 64 + (t - 192)];
    coef[t] = v;
  } else {
    const float* src = (y == 1 ? W2 : W3) + (size_t)d * 4096;
    const int hibase = (y == 1 ? REC_W2H : REC_W3H);
    for (int idx = t; idx < 4096; idx += 256)
      tile[(idx >> 6) * 65 + (idx & 63)] = src[idx];   // tile[kin][o]
    __syncthreads();
    const int tt = t & 127;
    const bool isLo = (t >= 128);
    const int o = tt >> 1, hh = tt & 1;
    __bf16* dst = (__bf16*)(rec + hibase + (isLo ? 8192 : 0));
#pragma unroll
    for (int cc = 0; cc < 4; ++cc) {
      const int cp = hh * 4 + cc;          // storage chunk position
      const int kc = cp ^ (o & 7);         // logical k-chunk held there
#pragma unroll
      for (int j = 0; j < 8; ++j) {
        float f = tile[(kc * 8 + j) * 65 + o];
        __bf16 h = (__bf16)f;
        dst[o * 64 + cp * 8 + j] = isLo ? (__bf16)(f - (float)h) : h;
      }
    }
  }
}

// ---------------------------------------------------------------------------
// main helpers
// ---------------------------------------------------------------------------
__device__ __forceinline__ void mid_layer(const char* __restrict__ smem, int whbase, int boff,
                                          f32x4 (&acc)[2][4], int wm, int wp, int l15, int lg, int x7) {
  const int co = (lg ^ x7) * 16;
  // bias preload into accumulators
#pragma unroll
  for (int mt = 0; mt < 2; ++mt) {
    f32x4 b = *(const f32x4*)(smem + REC_COEF + boff + wm * 128 + mt * 64 + lg * 16);
#pragma unroll
    for (int nt = 0; nt < 4; ++nt) acc[mt][nt] = b;
  }
  int aw[2], ab[4];
#pragma unroll
  for (int mt = 0; mt < 2; ++mt) aw[mt] = whbase + (wm * 32 + mt * 16 + l15) * 128 + co;
#pragma unroll
  for (int nt = 0; nt < 4; ++nt) ab[nt] = ACT_HI + (wp * 64 + nt * 16 + l15) * 128 + co;

#pragma unroll
  for (int ks = 0; ks < 2; ++ks) {
    const int kx = ks * 64;   // XOR on chunk bit: logical k-chunk += 4
    bf16x8 ah[2], al[2], bh[4], bl[4];
#pragma unroll
    for (int mt = 0; mt < 2; ++mt) {
      const char* p = smem + (aw[mt] ^ kx);
      ah[mt] = *(const bf16x8*)p;
      al[mt] = *(const bf16x8*)(p + 8192);    // lo twin, immediate offset
    }
#pragma unroll
    for (int nt = 0; nt < 4; ++nt) {
      const char* p = smem + (ab[nt] ^ kx);
      bh[nt] = *(const bf16x8*)p;
      bl[nt] = *(const bf16x8*)(p + 16384);   // lo twin
    }
#pragma unroll
    for (int mt = 0; mt < 2; ++mt)
#pragma unroll
      for (int nt = 0; nt < 4; ++nt)
        acc[mt][nt] = __builtin_amdgcn_mfma_f32_16x16x32_bf16(ah[mt], bh[nt], acc[mt][nt], 0, 0, 0);
#pragma unroll
    for (int mt = 0; mt < 2; ++mt)
#pragma unroll
      for (int nt = 0; nt < 4; ++nt)
        acc[mt][nt] = __builtin_amdgcn_mfma_f32_16x16x32_bf16(ah[mt], bl[nt], acc[mt][nt], 0, 0, 0);
#pragma unroll
    for (int mt = 0; mt < 2; ++mt)
#pragma unroll
      for (int nt = 0; nt < 4; ++nt)
        acc[mt][nt] = __builtin_amdgcn_mfma_f32_16x16x32_bf16(al[mt], bh[nt], acc[mt][nt], 0, 0, 0);
  }
}

__device__ __forceinline__ void transition(f32x4 (&acc)[2][4], char* __restrict__ smem,
                                           int wm, int wp, int l15, int lg, int x7) {
  const int h8 = (lg & 1) * 8;
#pragma unroll
  for (int mt = 0; mt < 2; ++mt) {
    const int c = wm * 4 + mt * 2 + (lg >> 1);
    const int coff = ((c ^ x7) * 16) + h8;
#pragma unroll
    for (int nt = 0; nt < 4; ++nt) {
      const int r = wp * 64 + nt * 16 + l15;
      bf16x4 hv, lv;
#pragma unroll
      for (int i = 0; i < 4; ++i) {
        float s = silu_f(acc[mt][nt][i]);
        __bf16 h = (__bf16)s;
        hv[i] = h;
        lv[i] = (__bf16)(s - (float)h);
      }
      char* p = smem + ACT_HI + r * 128 + coff;
      *(bf16x4*)p = hv;
      *(bf16x4*)(p + 16384) = lv;
    }
  }
}

// ---------------------------------------------------------------------------
// main: one block per (d, 128-row tile); 4 waves = 2 feat-halves x 2 row-halves
// ---------------------------------------------------------------------------
__global__ __launch_bounds__(256, 2)
void mlp_main(const float* __restrict__ z, const char* __restrict__ ws,
              const float* __restrict__ bo, float* __restrict__ out) {
  __shared__ __align__(16) char smem[LDS_SIZE];

  const int bx  = (int)blockIdx.x;
  const int swz = (bx & 7) * 1024 + (bx >> 3);   // 8192 blocks, bijective XCD chunking
  const int d   = swz >> 5;
  const int b0  = (swz & 31) * BT;

  const int t    = (int)threadIdx.x;
  const int lane = t & 63;
  const int wave = t >> 6;
  const int wm  = wave & 1;
  const int wp  = wave >> 1;
  const int l15 = lane & 15;
  const int lg  = lane >> 4;
  const int x7  = l15 & 7;

  // ---- z fragments: direct load + hi/lo split, select by k-slot parity ----
  bf16x8 zf[4];
#pragma unroll
  for (int nt = 0; nt < 4; ++nt) {
    const int r = b0 + wp * 64 + nt * 16 + l15;
    const float* zp = z + ((size_t)r * NDIM + d) * LDIM;
    float4 q0 = *(const float4*)zp;
    float4 q1 = *(const float4*)(zp + 4);
    float f[8] = {q0.x, q0.y, q0.z, q0.w, q1.x, q1.y, q1.z, q1.w};
    bf16x8 hv, lv;
#pragma unroll
    for (int j = 0; j < 8; ++j) {
      __bf16 h = (__bf16)f[j];
      hv[j] = h;
      lv[j] = (__bf16)(f[j] - (float)h);
    }
    zf[nt] = (lg & 1) ? lv : hv;   // lg 0,2 -> hi; lg 1,3 -> lo (lg3 hits zero A-frag)
  }

  // ---- stage weight record (36864 B linear) ----
  {
    const float4* gsrc = (const float4*)(ws + (size_t)d * REC_SIZE);
    float4* ldst = (float4*)smem;
    for (int i = t; i < REC_SIZE / 16; i += 256) ldst[i] = gsrc[i];
  }
  __syncthreads();  // A

  f32x4 acc[2][4];

  // ---- layer 1: A = [W1hi | W1hi | W1lo | 0], B = [zhi | zlo | zhi | zlo] ----
  {
    bf16x8 a1[2];
#pragma unroll
    for (int mt = 0; mt < 2; ++mt) {
      if (lg < 3) {
        a1[mt] = *(const bf16x8*)(smem + REC_W1P + (wm * 32 + mt * 16 + l15) * 48 + lg * 16);
      } else {
        a1[mt] = (bf16x8)((__bf16)0.0f);   // k-slots 24-31 zero => B garbage there is harmless
      }
    }
#pragma unroll
    for (int mt = 0; mt < 2; ++mt) {
      f32x4 b = *(const f32x4*)(smem + REC_COEF + wm * 128 + mt * 64 + lg * 16);  // b1
#pragma unroll
      for (int nt = 0; nt < 4; ++nt) acc[mt][nt] = b;
    }
#pragma unroll
    for (int mt = 0; mt < 2; ++mt)
#pragma unroll
      for (int nt = 0; nt < 4; ++nt)
        acc[mt][nt] = __builtin_amdgcn_mfma_f32_16x16x32_bf16(a1[mt], zf[nt], acc[mt][nt], 0, 0, 0);
  }

  transition(acc, smem, wm, wp, l15, lg, x7);
  __syncthreads();  // B: act1 ready

  mid_layer(smem, REC_W2H, 256, acc, wm, wp, l15, lg, x7);
  __syncthreads();  // C: act1 fully consumed
  transition(acc, smem, wm, wp, l15, lg, x7);
  __syncthreads();  // D: act2 ready

  mid_layer(smem, REC_W3H, 512, acc, wm, wp, l15, lg, x7);

  // ---- output: out[r] = sum_f silu(h3[f]) * Wo[f] + bo ----
  float* outBuf = (float*)(smem + OUTBUF);
  f32x4 wof[2];
#pragma unroll
  for (int mt = 0; mt < 2; ++mt)
    wof[mt] = *(const f32x4*)(smem + REC_COEF + 768 + wm * 128 + mt * 64 + lg * 16);
#pragma unroll
  for (int nt = 0; nt < 4; ++nt) {
    float part = 0.0f;
#pragma unroll
    for (int mt = 0; mt < 2; ++mt)
#pragma unroll
      for (int i = 0; i < 4; ++i)
        part += silu_f(acc[mt][nt][i]) * wof[mt][i];
    part += __shfl_xor(part, 16);
    part += __shfl_xor(part, 32);
    if (lg == 0) outBuf[wm * 128 + wp * 64 + nt * 16 + l15] = part;
  }
  __syncthreads();  // E
  if (t < BT) out[(size_t)(b0 + t) * NDIM + d] = outBuf[t] + outBuf[128 + t] + bo[d];
}

// ---------------------------------------------------------------------------
extern "C" void kernel_launch(void* const* d_in, const int* in_sizes, int n_in,
                              void* d_out, int out_size, void* d_ws, size_t ws_size,
                              hipStream_t stream) {
  const float* z  = (const float*)d_in[0];
  const float* W1 = (const float*)d_in[1];
  const float* b1 = (const float*)d_in[2];
  const float* W2 = (const float*)d_in[3];
  const float* b2 = (const float*)d_in[4];
  const float* W3 = (const float*)d_in[5];
  const float* b3 = (const float*)d_in[6];
  const float* Wo = (const float*)d_in[7];
  const float* bo = (const float*)d_in[8];
  float* out = (float*)d_out;
  char* ws = (char*)d_ws;

  setup_weights<<<dim3(NDIM, 3), 256, 0, stream>>>(W1, b1, W2, b2, W3, b3, Wo, ws);
  mlp_main<<<NDIM * (BDIM / BT), 256, 0, stream>>>(z, ws, bo, out);
}

// Round 6
// 208.902 us; speedup vs baseline: 1.2644x; 1.0273x over previous
//
#include <hip/hip_runtime.h>
#include <hip/hip_bf16.h>

// FactorizedGenerator: per-coordinate MLP 8 -> 64 -> 64 -> 64 -> 1 (SiLU), D=256, B=4096.
// Split-bf16 (hi+lo) MFMA emulation of fp32 GEMMs, transposed compute D = W^T @ H^T.
// R6: weights NOT staged in LDS — A-frags read direct from global packed records
//     (L2-resident per XCD via swizzle). LDS = act only (33.8KB -> 4 blocks/CU).
//     setup_weights store path rewritten coalesced (was ~76us of scattered 2B stores).

#define NDIM 256
#define LDIM 8
#define HDIM 64
#define BDIM 4096
#define BT   128

// per-d weight record layout (bytes) — plain (no swizzle; global reads don't bank-conflict)
#define REC_W1P   0        // [64][24] bf16: ks 0-7 W1hi, 8-15 W1hi, 16-23 W1lo
#define REC_W2H   3072     // [64][64] bf16 W^T (out-feat-major); lo twin at +8192
#define REC_W2L   11264
#define REC_W3H   19456
#define REC_W3L   27648
#define REC_COEF  35840    // 256 f32: [0,64) b1, [64,128) b2, [128,192) b3, [192,256) Wo
#define REC_SIZE  36864

// LDS: activations only
#define ACT_HI    0        // [128][64] bf16, 16B-chunk XOR swizzle: pos = chunk ^ (row&7)
#define ACT_LO    16384
#define OUTBUF    32768    // 256 f32
#define LDS_SIZE  33792    // -> 4 blocks/CU by LDS

typedef __bf16 bf16x8 __attribute__((ext_vector_type(8)));
typedef __bf16 bf16x4 __attribute__((ext_vector_type(4)));
typedef float  f32x4  __attribute__((ext_vector_type(4)));

__device__ __forceinline__ float silu_f(float x) {
  return x * __builtin_amdgcn_rcpf(1.0f + __expf(-x));
}

// ---------------------------------------------------------------------------
// setup: fp32 weights -> packed bf16 hi/lo records. grid (256, 3).
// ---------------------------------------------------------------------------
__global__ void setup_weights(const float* __restrict__ W1, const float* __restrict__ b1,
                              const float* __restrict__ W2, const float* __restrict__ b2,
                              const float* __restrict__ W3, const float* __restrict__ b3,
                              const float* __restrict__ Wo, char* __restrict__ ws) {
  const int d = blockIdx.x;
  const int y = blockIdx.y;
  const int t = threadIdx.x;
  __shared__ float tile[64 * 65];
  char* rec = ws + (size_t)d * REC_SIZE;

  if (y == 0) {
    // W1 (8x64) + coef
    for (int idx = t; idx < LDIM * HDIM; idx += 256)
      tile[(idx >> 6) * 65 + (idx & 63)] = W1[d * LDIM * HDIM + idx];   // tile[l][o]
    __syncthreads();
    if (t < 64) {
      __bf16* w1p = (__bf16*)(rec + REC_W1P) + t * 24;
#pragma unroll
      for (int ks = 0; ks < 8; ++ks) {
        float f = tile[ks * 65 + t];
        __bf16 h = (__bf16)f;
        w1p[ks] = h;
        w1p[8 + ks] = h;
        w1p[16 + ks] = (__bf16)(f - (float)h);
      }
    }
    float* coef = (float*)(rec + REC_COEF);
    float v;
    if (t < 64)       v = b1[d * 64 + t];
    else if (t < 128) v = b2[d * 64 + (t - 64)];
    else if (t < 192) v = b3[d * 64 + (t - 128)];
    else              v = Wo[d * 64 + (t - 192)];
    coef[t] = v;
  } else {
    const float* src = (y == 1 ? W2 : W3) + (size_t)d * 4096;
    const int hibase = (y == 1 ? REC_W2H : REC_W3H);
    for (int idx = t; idx < 4096; idx += 256)
      tile[(idx >> 6) * 65 + (idx & 63)] = src[idx];   // tile[kin][o]
    __syncthreads();
    // coalesced pack: thread -> (o = t>>2, kin quarter q = t&3), 32B hi + 32B lo
    const int o = t >> 2;
    const int q = t & 3;
    bf16x8 h0, h1, l0, l1;
#pragma unroll
    for (int j = 0; j < 8; ++j) {
      float f = tile[(q * 16 + j) * 65 + o];
      __bf16 h = (__bf16)f;
      h0[j] = h; l0[j] = (__bf16)(f - (float)h);
      float g = tile[(q * 16 + 8 + j) * 65 + o];
      __bf16 hg = (__bf16)g;
      h1[j] = hg; l1[j] = (__bf16)(g - (float)hg);
    }
    char* dst = rec + hibase + o * 128 + q * 32;
    *(bf16x8*)(dst)              = h0;
    *(bf16x8*)(dst + 16)         = h1;
    *(bf16x8*)(dst + 8192)       = l0;
    *(bf16x8*)(dst + 8192 + 16)  = l1;
  }
}

// ---------------------------------------------------------------------------
// main helpers
// ---------------------------------------------------------------------------
// mid layer: A-frags from GLOBAL record (L2-hot), B-frags from swizzled LDS act.
__device__ __forceinline__ void mid_layer(const char* __restrict__ wh, const float* __restrict__ biasf,
                                          const char* __restrict__ smem, f32x4 (&acc)[2][4],
                                          int wm, int wp, int l15, int lg, int x7) {
  const int co = (lg ^ x7) * 16;
  // bias preload into accumulators
#pragma unroll
  for (int mt = 0; mt < 2; ++mt) {
    f32x4 b = *(const f32x4*)(biasf + wm * 32 + mt * 16 + lg * 4);
#pragma unroll
    for (int nt = 0; nt < 4; ++nt) acc[mt][nt] = b;
  }
  const char* aw[2];
  int ab[4];
#pragma unroll
  for (int mt = 0; mt < 2; ++mt) aw[mt] = wh + (wm * 32 + mt * 16 + l15) * 128 + lg * 16;
#pragma unroll
  for (int nt = 0; nt < 4; ++nt) ab[nt] = ACT_HI + (wp * 64 + nt * 16 + l15) * 128 + co;

#pragma unroll
  for (int ks = 0; ks < 2; ++ks) {
    const int kx = ks * 64;   // LDS act: XOR on chunk bit (swizzle); global A: additive
    bf16x8 ah[2], al[2], bh[4], bl[4];
#pragma unroll
    for (int mt = 0; mt < 2; ++mt) {
      const char* p = aw[mt] + kx;
      ah[mt] = *(const bf16x8*)p;
      al[mt] = *(const bf16x8*)(p + 8192);    // lo twin
    }
#pragma unroll
    for (int nt = 0; nt < 4; ++nt) {
      const char* p = smem + (ab[nt] ^ kx);
      bh[nt] = *(const bf16x8*)p;
      bl[nt] = *(const bf16x8*)(p + 16384);   // act lo twin
    }
#pragma unroll
    for (int mt = 0; mt < 2; ++mt)
#pragma unroll
      for (int nt = 0; nt < 4; ++nt)
        acc[mt][nt] = __builtin_amdgcn_mfma_f32_16x16x32_bf16(ah[mt], bh[nt], acc[mt][nt], 0, 0, 0);
#pragma unroll
    for (int mt = 0; mt < 2; ++mt)
#pragma unroll
      for (int nt = 0; nt < 4; ++nt)
        acc[mt][nt] = __builtin_amdgcn_mfma_f32_16x16x32_bf16(ah[mt], bl[nt], acc[mt][nt], 0, 0, 0);
#pragma unroll
    for (int mt = 0; mt < 2; ++mt)
#pragma unroll
      for (int nt = 0; nt < 4; ++nt)
        acc[mt][nt] = __builtin_amdgcn_mfma_f32_16x16x32_bf16(al[mt], bh[nt], acc[mt][nt], 0, 0, 0);
  }
}

__device__ __forceinline__ void transition(f32x4 (&acc)[2][4], char* __restrict__ smem,
                                           int wm, int wp, int l15, int lg, int x7) {
  const int h8 = (lg & 1) * 8;
#pragma unroll
  for (int mt = 0; mt < 2; ++mt) {
    const int c = wm * 4 + mt * 2 + (lg >> 1);
    const int coff = ((c ^ x7) * 16) + h8;
#pragma unroll
    for (int nt = 0; nt < 4; ++nt) {
      const int r = wp * 64 + nt * 16 + l15;
      bf16x4 hv, lv;
#pragma unroll
      for (int i = 0; i < 4; ++i) {
        float s = silu_f(acc[mt][nt][i]);
        __bf16 h = (__bf16)s;
        hv[i] = h;
        lv[i] = (__bf16)(s - (float)h);
      }
      char* p = smem + ACT_HI + r * 128 + coff;
      *(bf16x4*)p = hv;
      *(bf16x4*)(p + 16384) = lv;
    }
  }
}

// ---------------------------------------------------------------------------
// main: one block per (d, 128-row tile); 4 waves = 2 feat-halves x 2 row-halves
// ---------------------------------------------------------------------------
__global__ __launch_bounds__(256, 3)
void mlp_main(const float* __restrict__ z, const char* __restrict__ ws,
              const float* __restrict__ bo, float* __restrict__ out) {
  __shared__ __align__(16) char smem[LDS_SIZE];

  const int bx  = (int)blockIdx.x;
  const int swz = (bx & 7) * 1024 + (bx >> 3);   // 8192 blocks, bijective XCD chunking
  const int d   = swz >> 5;
  const int b0  = (swz & 31) * BT;

  const int t    = (int)threadIdx.x;
  const int lane = t & 63;
  const int wave = t >> 6;
  const int wm  = wave & 1;
  const int wp  = wave >> 1;
  const int l15 = lane & 15;
  const int lg  = lane >> 4;
  const int x7  = l15 & 7;

  const char* rec   = ws + (size_t)d * REC_SIZE;
  const float* coef = (const float*)(rec + REC_COEF);

  // ---- z fragments: direct load + hi/lo split, select by k-slot parity ----
  bf16x8 zf[4];
#pragma unroll
  for (int nt = 0; nt < 4; ++nt) {
    const int r = b0 + wp * 64 + nt * 16 + l15;
    const float* zp = z + ((size_t)r * NDIM + d) * LDIM;
    float4 q0 = *(const float4*)zp;
    float4 q1 = *(const float4*)(zp + 4);
    float f[8] = {q0.x, q0.y, q0.z, q0.w, q1.x, q1.y, q1.z, q1.w};
    bf16x8 hv, lv;
#pragma unroll
    for (int j = 0; j < 8; ++j) {
      __bf16 h = (__bf16)f[j];
      hv[j] = h;
      lv[j] = (__bf16)(f[j] - (float)h);
    }
    zf[nt] = (lg & 1) ? lv : hv;   // lg 0,2 -> hi; lg 1,3 -> lo (lg3 hits zero A-frag)
  }

  f32x4 acc[2][4];

  // ---- layer 1: A = [W1hi | W1hi | W1lo | 0] from global, B = [zhi | zlo | zhi | zlo] ----
  {
    bf16x8 a1[2];
#pragma unroll
    for (int mt = 0; mt < 2; ++mt) {
      if (lg < 3) {
        a1[mt] = *(const bf16x8*)(rec + REC_W1P + (wm * 32 + mt * 16 + l15) * 48 + lg * 16);
      } else {
        a1[mt] = (bf16x8)((__bf16)0.0f);
      }
    }
#pragma unroll
    for (int mt = 0; mt < 2; ++mt) {
      f32x4 b = *(const f32x4*)(coef + wm * 32 + mt * 16 + lg * 4);   // b1
#pragma unroll
      for (int nt = 0; nt < 4; ++nt) acc[mt][nt] = b;
    }
#pragma unroll
    for (int mt = 0; mt < 2; ++mt)
#pragma unroll
      for (int nt = 0; nt < 4; ++nt)
        acc[mt][nt] = __builtin_amdgcn_mfma_f32_16x16x32_bf16(a1[mt], zf[nt], acc[mt][nt], 0, 0, 0);
  }

  transition(acc, smem, wm, wp, l15, lg, x7);
  __syncthreads();  // B: act1 ready

  mid_layer(rec + REC_W2H, coef + 64, smem, acc, wm, wp, l15, lg, x7);
  __syncthreads();  // C: act1 fully consumed
  transition(acc, smem, wm, wp, l15, lg, x7);
  __syncthreads();  // D: act2 ready

  mid_layer(rec + REC_W3H, coef + 128, smem, acc, wm, wp, l15, lg, x7);

  // ---- output: out[r] = sum_f silu(h3[f]) * Wo[f] + bo ----
  float* outBuf = (float*)(smem + OUTBUF);
  f32x4 wof[2];
#pragma unroll
  for (int mt = 0; mt < 2; ++mt)
    wof[mt] = *(const f32x4*)(coef + 192 + wm * 32 + mt * 16 + lg * 4);
#pragma unroll
  for (int nt = 0; nt < 4; ++nt) {
    float part = 0.0f;
#pragma unroll
    for (int mt = 0; mt < 2; ++mt)
#pragma unroll
      for (int i = 0; i < 4; ++i)
        part += silu_f(acc[mt][nt][i]) * wof[mt][i];
    part += __shfl_xor(part, 16);
    part += __shfl_xor(part, 32);
    if (lg == 0) outBuf[wm * 128 + wp * 64 + nt * 16 + l15] = part;
  }
  __syncthreads();  // E
  if (t < BT) out[(size_t)(b0 + t) * NDIM + d] = outBuf[t] + outBuf[128 + t] + bo[d];
}

// ---------------------------------------------------------------------------
extern "C" void kernel_launch(void* const* d_in, const int* in_sizes, int n_in,
                              void* d_out, int out_size, void* d_ws, size_t ws_size,
                              hipStream_t stream) {
  const float* z  = (const float*)d_in[0];
  const float* W1 = (const float*)d_in[1];
  const float* b1 = (const float*)d_in[2];
  const float* W2 = (const float*)d_in[3];
  const float* b2 = (const float*)d_in[4];
  const float* W3 = (const float*)d_in[5];
  const float* b3 = (const float*)d_in[6];
  const float* Wo = (const float*)d_in[7];
  const float* bo = (const float*)d_in[8];
  float* out = (float*)d_out;
  char* ws = (char*)d_ws;

  setup_weights<<<dim3(NDIM, 3), 256, 0, stream>>>(W1, b1, W2, b2, W3, b3, Wo, ws);
  mlp_main<<<NDIM * (BDIM / BT), 256, 0, stream>>>(z, ws, bo, out);
}

// Round 7
// 198.370 us; speedup vs baseline: 1.3315x; 1.0531x over previous
//
#include <hip/hip_runtime.h>
#include <hip/hip_bf16.h>

// FactorizedGenerator: per-coordinate MLP 8 -> 64 -> 64 -> 64 -> 1 (SiLU), D=256, B=4096.
// Split-bf16 MFMA emulation of fp32 GEMMs, transposed compute D = W^T @ H^T.
// R7: drop the activation lo-split (act stored as plain bf16). Weights & z keep hi/lo
//     splits (exact). Cuts ~25% of dynamic instructions (the R6 finding: kernel is
//     issue-bound — occupancy doubling changed nothing). LDS 17.4KB -> ~8 blocks/CU.

#define NDIM 256
#define LDIM 8
#define HDIM 64
#define BDIM 4096
#define BT   128

// per-d weight record layout (bytes) — plain (global reads don't bank-conflict)
#define REC_W1P   0        // [64][24] bf16: ks 0-7 W1hi, 8-15 W1hi, 16-23 W1lo
#define REC_W2H   3072     // [64][64] bf16 W^T (out-feat-major); lo twin at +8192
#define REC_W2L   11264
#define REC_W3H   19456
#define REC_W3L   27648
#define REC_COEF  35840    // 256 f32: [0,64) b1, [64,128) b2, [128,192) b3, [192,256) Wo
#define REC_SIZE  36864

// LDS: activations (hi only) + output buffer
#define ACT_HI    0        // [128][64] bf16, 16B-chunk XOR swizzle: pos = chunk ^ (row&7)
#define OUTBUF    16384    // 256 f32
#define LDS_SIZE  17408    // -> ~8 blocks/CU by LDS

typedef __bf16 bf16x8 __attribute__((ext_vector_type(8)));
typedef __bf16 bf16x4 __attribute__((ext_vector_type(4)));
typedef float  f32x4  __attribute__((ext_vector_type(4)));

__device__ __forceinline__ float silu_f(float x) {
  return x * __builtin_amdgcn_rcpf(1.0f + __expf(-x));
}

// ---------------------------------------------------------------------------
// setup: fp32 weights -> packed bf16 hi/lo records. grid (256, 3).
// ---------------------------------------------------------------------------
__global__ void setup_weights(const float* __restrict__ W1, const float* __restrict__ b1,
                              const float* __restrict__ W2, const float* __restrict__ b2,
                              const float* __restrict__ W3, const float* __restrict__ b3,
                              const float* __restrict__ Wo, char* __restrict__ ws) {
  const int d = blockIdx.x;
  const int y = blockIdx.y;
  const int t = threadIdx.x;
  __shared__ float tile[64 * 65];
  char* rec = ws + (size_t)d * REC_SIZE;

  if (y == 0) {
    // W1 (8x64) + coef
    for (int idx = t; idx < LDIM * HDIM; idx += 256)
      tile[(idx >> 6) * 65 + (idx & 63)] = W1[d * LDIM * HDIM + idx];   // tile[l][o]
    __syncthreads();
    if (t < 64) {
      __bf16* w1p = (__bf16*)(rec + REC_W1P) + t * 24;
#pragma unroll
      for (int ks = 0; ks < 8; ++ks) {
        float f = tile[ks * 65 + t];
        __bf16 h = (__bf16)f;
        w1p[ks] = h;
        w1p[8 + ks] = h;
        w1p[16 + ks] = (__bf16)(f - (float)h);
      }
    }
    float* coef = (float*)(rec + REC_COEF);
    float v;
    if (t < 64)       v = b1[d * 64 + t];
    else if (t < 128) v = b2[d * 64 + (t - 64)];
    else if (t < 192) v = b3[d * 64 + (t - 128)];
    else              v = Wo[d * 64 + (t - 192)];
    coef[t] = v;
  } else {
    const float* src = (y == 1 ? W2 : W3) + (size_t)d * 4096;
    const int hibase = (y == 1 ? REC_W2H : REC_W3H);
    for (int idx = t; idx < 4096; idx += 256)
      tile[(idx >> 6) * 65 + (idx & 63)] = src[idx];   // tile[kin][o]
    __syncthreads();
    // coalesced pack: thread -> (o = t>>2, kin quarter q = t&3), 32B hi + 32B lo
    const int o = t >> 2;
    const int q = t & 3;
    bf16x8 h0, h1, l0, l1;
#pragma unroll
    for (int j = 0; j < 8; ++j) {
      float f = tile[(q * 16 + j) * 65 + o];
      __bf16 h = (__bf16)f;
      h0[j] = h; l0[j] = (__bf16)(f - (float)h);
      float g = tile[(q * 16 + 8 + j) * 65 + o];
      __bf16 hg = (__bf16)g;
      h1[j] = hg; l1[j] = (__bf16)(g - (float)hg);
    }
    char* dst = rec + hibase + o * 128 + q * 32;
    *(bf16x8*)(dst)              = h0;
    *(bf16x8*)(dst + 16)         = h1;
    *(bf16x8*)(dst + 8192)       = l0;
    *(bf16x8*)(dst + 8192 + 16)  = l1;
  }
}

// ---------------------------------------------------------------------------
// main helpers
// ---------------------------------------------------------------------------
// mid layer: acc = (Wh + Wl) * act_hi. A-frags from GLOBAL record (L2-hot),
// B-frags (act, bf16 hi only) from swizzled LDS.
__device__ __forceinline__ void mid_layer(const char* __restrict__ wh, const float* __restrict__ biasf,
                                          const char* __restrict__ smem, f32x4 (&acc)[2][4],
                                          int wm, int wp, int l15, int lg, int x7) {
  const int co = (lg ^ x7) * 16;
  // bias preload into accumulators
#pragma unroll
  for (int mt = 0; mt < 2; ++mt) {
    f32x4 b = *(const f32x4*)(biasf + wm * 32 + mt * 16 + lg * 4);
#pragma unroll
    for (int nt = 0; nt < 4; ++nt) acc[mt][nt] = b;
  }
  const char* aw[2];
  int ab[4];
#pragma unroll
  for (int mt = 0; mt < 2; ++mt) aw[mt] = wh + (wm * 32 + mt * 16 + l15) * 128 + lg * 16;
#pragma unroll
  for (int nt = 0; nt < 4; ++nt) ab[nt] = ACT_HI + (wp * 64 + nt * 16 + l15) * 128 + co;

#pragma unroll
  for (int ks = 0; ks < 2; ++ks) {
    const int kx = ks * 64;   // LDS act: XOR on chunk bit (swizzle); global A: additive
    bf16x8 ah[2], al[2], bh[4];
#pragma unroll
    for (int mt = 0; mt < 2; ++mt) {
      const char* p = aw[mt] + kx;
      ah[mt] = *(const bf16x8*)p;
      al[mt] = *(const bf16x8*)(p + 8192);    // W lo twin
    }
#pragma unroll
    for (int nt = 0; nt < 4; ++nt)
      bh[nt] = *(const bf16x8*)(smem + (ab[nt] ^ kx));
#pragma unroll
    for (int mt = 0; mt < 2; ++mt)
#pragma unroll
      for (int nt = 0; nt < 4; ++nt)
        acc[mt][nt] = __builtin_amdgcn_mfma_f32_16x16x32_bf16(ah[mt], bh[nt], acc[mt][nt], 0, 0, 0);
#pragma unroll
    for (int mt = 0; mt < 2; ++mt)
#pragma unroll
      for (int nt = 0; nt < 4; ++nt)
        acc[mt][nt] = __builtin_amdgcn_mfma_f32_16x16x32_bf16(al[mt], bh[nt], acc[mt][nt], 0, 0, 0);
  }
}

__device__ __forceinline__ void transition(f32x4 (&acc)[2][4], char* __restrict__ smem,
                                           int wm, int wp, int l15, int lg, int x7) {
  const int h8 = (lg & 1) * 8;
#pragma unroll
  for (int mt = 0; mt < 2; ++mt) {
    const int c = wm * 4 + mt * 2 + (lg >> 1);
    const int coff = ((c ^ x7) * 16) + h8;
#pragma unroll
    for (int nt = 0; nt < 4; ++nt) {
      const int r = wp * 64 + nt * 16 + l15;
      bf16x4 hv;
#pragma unroll
      for (int i = 0; i < 4; ++i)
        hv[i] = (__bf16)silu_f(acc[mt][nt][i]);
      *(bf16x4*)(smem + ACT_HI + r * 128 + coff) = hv;
    }
  }
}

// ---------------------------------------------------------------------------
// main: one block per (d, 128-row tile); 4 waves = 2 feat-halves x 2 row-halves
// ---------------------------------------------------------------------------
__global__ __launch_bounds__(256, 3)
void mlp_main(const float* __restrict__ z, const char* __restrict__ ws,
              const float* __restrict__ bo, float* __restrict__ out) {
  __shared__ __align__(16) char smem[LDS_SIZE];

  const int bx  = (int)blockIdx.x;
  const int swz = (bx & 7) * 1024 + (bx >> 3);   // 8192 blocks, bijective XCD chunking
  const int d   = swz >> 5;
  const int b0  = (swz & 31) * BT;

  const int t    = (int)threadIdx.x;
  const int lane = t & 63;
  const int wave = t >> 6;
  const int wm  = wave & 1;
  const int wp  = wave >> 1;
  const int l15 = lane & 15;
  const int lg  = lane >> 4;
  const int x7  = l15 & 7;

  const char* rec   = ws + (size_t)d * REC_SIZE;
  const float* coef = (const float*)(rec + REC_COEF);

  // ---- z fragments: direct load + hi/lo split, select by k-slot parity ----
  bf16x8 zf[4];
#pragma unroll
  for (int nt = 0; nt < 4; ++nt) {
    const int r = b0 + wp * 64 + nt * 16 + l15;
    const float* zp = z + ((size_t)r * NDIM + d) * LDIM;
    float4 q0 = *(const float4*)zp;
    float4 q1 = *(const float4*)(zp + 4);
    float f[8] = {q0.x, q0.y, q0.z, q0.w, q1.x, q1.y, q1.z, q1.w};
    bf16x8 hv, lv;
#pragma unroll
    for (int j = 0; j < 8; ++j) {
      __bf16 h = (__bf16)f[j];
      hv[j] = h;
      lv[j] = (__bf16)(f[j] - (float)h);
    }
    zf[nt] = (lg & 1) ? lv : hv;   // lg 0,2 -> hi; lg 1,3 -> lo (lg3 hits zero A-frag)
  }

  f32x4 acc[2][4];

  // ---- layer 1: A = [W1hi | W1hi | W1lo | 0] from global, B = [zhi | zlo | zhi | zlo] ----
  {
    bf16x8 a1[2];
#pragma unroll
    for (int mt = 0; mt < 2; ++mt) {
      if (lg < 3) {
        a1[mt] = *(const bf16x8*)(rec + REC_W1P + (wm * 32 + mt * 16 + l15) * 48 + lg * 16);
      } else {
        a1[mt] = (bf16x8)((__bf16)0.0f);
      }
    }
#pragma unroll
    for (int mt = 0; mt < 2; ++mt) {
      f32x4 b = *(const f32x4*)(coef + wm * 32 + mt * 16 + lg * 4);   // b1
#pragma unroll
      for (int nt = 0; nt < 4; ++nt) acc[mt][nt] = b;
    }
#pragma unroll
    for (int mt = 0; mt < 2; ++mt)
#pragma unroll
      for (int nt = 0; nt < 4; ++nt)
        acc[mt][nt] = __builtin_amdgcn_mfma_f32_16x16x32_bf16(a1[mt], zf[nt], acc[mt][nt], 0, 0, 0);
  }

  transition(acc, smem, wm, wp, l15, lg, x7);
  __syncthreads();  // B: act1 ready

  mid_layer(rec + REC_W2H, coef + 64, smem, acc, wm, wp, l15, lg, x7);
  __syncthreads();  // C: act1 fully consumed
  transition(acc, smem, wm, wp, l15, lg, x7);
  __syncthreads();  // D: act2 ready

  mid_layer(rec + REC_W3H, coef + 128, smem, acc, wm, wp, l15, lg, x7);

  // ---- output: out[r] = sum_f silu(h3[f]) * Wo[f] + bo ----
  float* outBuf = (float*)(smem + OUTBUF);
  f32x4 wof[2];
#pragma unroll
  for (int mt = 0; mt < 2; ++mt)
    wof[mt] = *(const f32x4*)(coef + 192 + wm * 32 + mt * 16 + lg * 4);
#pragma unroll
  for (int nt = 0; nt < 4; ++nt) {
    float part = 0.0f;
#pragma unroll
    for (int mt = 0; mt < 2; ++mt)
#pragma unroll
      for (int i = 0; i < 4; ++i)
        part += silu_f(acc[mt][nt][i]) * wof[mt][i];
    part += __shfl_xor(part, 16);
    part += __shfl_xor(part, 32);
    if (lg == 0) outBuf[wm * 128 + wp * 64 + nt * 16 + l15] = part;
  }
  __syncthreads();  // E
  if (t < BT) out[(size_t)(b0 + t) * NDIM + d] = outBuf[t] + outBuf[128 + t] + bo[d];
}

// ---------------------------------------------------------------------------
extern "C" void kernel_launch(void* const* d_in, const int* in_sizes, int n_in,
                              void* d_out, int out_size, void* d_ws, size_t ws_size,
                              hipStream_t stream) {
  const float* z  = (const float*)d_in[0];
  const float* W1 = (const float*)d_in[1];
  const float* b1 = (const float*)d_in[2];
  const float* W2 = (const float*)d_in[3];
  const float* b2 = (const float*)d_in[4];
  const float* W3 = (const float*)d_in[5];
  const float* b3 = (const float*)d_in[6];
  const float* Wo = (const float*)d_in[7];
  const float* bo = (const float*)d_in[8];
  float* out = (float*)d_out;
  char* ws = (char*)d_ws;

  setup_weights<<<dim3(NDIM, 3), 256, 0, stream>>>(W1, b1, W2, b2, W3, b3, Wo, ws);
  mlp_main<<<NDIM * (BDIM / BT), 256, 0, stream>>>(z, ws, bo, out);
}